// Round 10
// baseline (104553.674 us; speedup 1.0000x reference)
//
#include <hip/hip_runtime.h>
#include <cstdint>
#include <cstddef>

// GRU decoder w/ Bahdanau attention, B=64 L=512 E=128 H=512 ENC=256 V=4 NL=2.
// R10: ONE BLOCK PER BATCH (64 blocks x 1024 threads). Zero cross-block
// synchronization: all recurrence state in LDS, phases split by
// __syncthreads only. f16 weights/operands with v_dot2_f32_f16 (2 MAC/inst).
// Weights stream from L2/L3 (shared by the ~8 lockstep blocks per XCD).
// Logits written directly to out (no reduce kernel). Plain launches only.

#define BB   64
#define LL   512
#define EE   128
#define HH   512
#define ED   256
#define VV   4
#define SOS  4
#define NT   1024

typedef unsigned int uint;
typedef unsigned short ushort8 __attribute__((ext_vector_type(8)));
typedef _Float16 h2v __attribute__((ext_vector_type(2)));

// ---------------- ws layout (bytes) ----------------
static const size_t OFF_KEYS = 0;          // f16 [64][512][512]   33,554,432
static const size_t OFF_ENCT = 33554432;   // f16 [64][256][512]   16,777,216
static const size_t OFF_WH   = 50331648;   // f16 [512][512]          524,288
static const size_t OFF_WHH0 = 50855936;   // f16 [1536][512]       1,572,864
static const size_t OFF_WHH1 = 52428800;   // f16 [1536][512]       1,572,864
static const size_t OFF_WIH1 = 54001664;   // f16 [1536][512]       1,572,864
static const size_t OFF_WIHC = 55574528;   // f16 [1536][256]         786,432
static const size_t OFF_GTOK = 56360960;   // f32 [6][1536]            36,864
static const size_t OFF_H0   = 56397824;   // f32 [64][512]           131,072
static const size_t OFF_H1   = 56528896;   // f32 [64][512]           131,072
// end ~56.7 MB

// ---------------- LDS layout (bytes), total 40,704 ----------------
#define L_H0F  0       // 2048  h0 f32[512]
#define L_H1F  2048    // 2048  h1 f32[512]
#define L_H0H  4096    // 1024  h0 packed f16 pairs uint[256]
#define L_H1H  5120    // 1024  h1 packed f16 pairs uint[256]
#define L_QB   6144    // 2112  q f32 [4][132] padded
#define L_VV   8256    // 2112  v f32 [4][132] padded
#define L_SCB  10368   // 2048  scores f32[512]
#define L_ATB  12416   // 2112  exp(scores) f32 [4][132] padded
#define L_CTXF 14528   // 1024  ctx f32[256]
#define L_CTXH 15552   // 512   ctx packed f16 pairs uint[128]
#define L_GH0  16064   // 6144  gh0 f32[1536]
#define L_GH1  22208   // 6144  gh1 f32[1536]
#define L_GI0  28352   // 6144  gi0 f32[1536]
#define L_GI1  34496   // 6144  gi1 f32[1536]
#define L_WRED 40640   // 64
#define L_TOT  40704

// ---------------- helpers ----------------
__device__ __forceinline__ float h2f(unsigned short u) {
  return (float)__builtin_bit_cast(_Float16, u);
}
__device__ __forceinline__ unsigned short f2h(float f) {
  return __builtin_bit_cast(unsigned short, (_Float16)f);
}
__device__ __forceinline__ uint packh(float a, float b) {
  return (uint)f2h(a) | ((uint)f2h(b) << 16);
}
__device__ __forceinline__ float fd2(uint w, uint h, float acc) {
#if __has_builtin(__builtin_amdgcn_fdot2)
  return __builtin_amdgcn_fdot2(__builtin_bit_cast(h2v, w),
                                __builtin_bit_cast(h2v, h), acc, false);
#else
  acc += h2f((unsigned short)(w & 0xffffu)) * h2f((unsigned short)(h & 0xffffu));
  acc += h2f((unsigned short)(w >> 16)) * h2f((unsigned short)(h >> 16));
  return acc;
#endif
}
__device__ __forceinline__ float tanh_fast(float x) {
  x = __builtin_amdgcn_fmed3f(x, -10.f, 10.f);
  float t = __builtin_amdgcn_exp2f(x * 2.8853900817779268f);
  return (t - 1.f) * __builtin_amdgcn_rcpf(t + 1.f);
}
__device__ __forceinline__ float sigmoid_fast(float x) {
  x = __builtin_amdgcn_fmed3f(x, -30.f, 30.f);
  float t = __builtin_amdgcn_exp2f(x * -1.4426950408889634f);
  return __builtin_amdgcn_rcpf(1.f + t);
}
__device__ __forceinline__ float exp_fast(float x) {
  return __builtin_amdgcn_exp2f(x * 1.4426950408889634f);
}

// ---------------- precompute kernels ----------------

// weights -> f16 (WihC = Wih0[:,128:384])
__global__ void k_prep(const float* Wh, const float* Whh0, const float* Whh1,
                       const float* Wih1, const float* Wih0, char* ws) {
  unsigned short* WhF   = (unsigned short*)(ws + OFF_WH);
  unsigned short* W0F   = (unsigned short*)(ws + OFF_WHH0);
  unsigned short* W1F   = (unsigned short*)(ws + OFF_WHH1);
  unsigned short* Wi1F  = (unsigned short*)(ws + OFF_WIH1);
  unsigned short* WicF  = (unsigned short*)(ws + OFF_WIHC);
  const int tot = 262144 + 786432 * 3 + 393216;
  for (int i = blockIdx.x * blockDim.x + threadIdx.x; i < tot; i += gridDim.x * blockDim.x) {
    if (i < 262144) WhF[i] = f2h(Wh[i]);
    else if (i < 262144 + 786432) { int j = i - 262144; W0F[j] = f2h(Whh0[j]); }
    else if (i < 262144 + 2 * 786432) { int j = i - 262144 - 786432; W1F[j] = f2h(Whh1[j]); }
    else if (i < 262144 + 3 * 786432) { int j = i - 262144 - 2 * 786432; Wi1F[j] = f2h(Wih1[j]); }
    else {
      int j = i - 262144 - 3 * 786432;
      int r = j >> 8, e = j & 255;
      WicF[j] = f2h(Wih0[(size_t)r * 384 + 128 + e]);
    }
  }
}

// keys f16: keys[b][l][h] = f16(enc[b][l][:] . Ws[h][:])
__global__ void k_keys(const float* enc, const float* Ws, char* ws) {
  unsigned short* keys = (unsigned short*)(ws + OFF_KEYS);
  __shared__ float et[32][ED];
  const int tid = threadIdx.x;
  const int row0 = blockIdx.x * 32;
  for (int r = 0; r < 32; ++r) et[r][tid] = enc[(size_t)(row0 + r) * ED + tid];
  __syncthreads();
  for (int hhh = 0; hhh < 2; ++hhh) {
    const int h = hhh * 256 + tid;
    float acc[32];
    #pragma unroll
    for (int ll = 0; ll < 32; ++ll) acc[ll] = 0.f;
    const float4* wrow = (const float4*)(Ws + (size_t)h * ED);
    for (int e4 = 0; e4 < 64; ++e4) {
      float4 w = wrow[e4];
      #pragma unroll
      for (int ll = 0; ll < 32; ++ll) {
        acc[ll] += w.x * et[ll][e4 * 4] + w.y * et[ll][e4 * 4 + 1]
                 + w.z * et[ll][e4 * 4 + 2] + w.w * et[ll][e4 * 4 + 3];
      }
    }
    for (int ll = 0; ll < 32; ++ll)
      keys[(size_t)(row0 + ll) * HH + h] = f2h(acc[ll]);
  }
}

// encT f16: enct[b][e][l] = f16(enc[b][l][e])
__global__ void k_encT(const float* enc, char* ws) {
  unsigned short* enct = (unsigned short*)(ws + OFF_ENCT);
  const int tot = BB * LL * ED;
  for (int i = blockIdx.x * blockDim.x + threadIdx.x; i < tot; i += gridDim.x * blockDim.x) {
    int b = i >> 17, l = (i >> 8) & 511, e = i & 255;
    enct[((size_t)b * ED + e) * LL + l] = f2h(enc[i]);
  }
}

// gi_tok[v][r] = bih0[r] + emb[v] . Wih0[r][0:128]   (f32)
__global__ void k_gitok(const float* emb, const float* Wih0, const float* bih0, char* ws) {
  float* gt = (float*)(ws + OFF_GTOK);
  const int vt = blockIdx.x;
  const int tid = threadIdx.x;
  __shared__ float ev[EE];
  if (tid < EE) ev[tid] = emb[(size_t)vt * EE + tid];
  __syncthreads();
  for (int r = tid; r < 1536; r += 256) {
    float a = bih0[r];
    const float* wr = Wih0 + (size_t)r * 384;
    for (int e = 0; e < EE; ++e) a += wr[e] * ev[e];
    gt[(size_t)vt * 1536 + r] = a;
  }
}

// init hidden (f32)
__global__ void k_init(const float* enc, const float* Winit, const float* binit, char* ws) {
  const int b = blockIdx.x;
  const int tid = threadIdx.x; // 256
  __shared__ float pooled[ED];
  float acc = 0.f;
  for (int l = 0; l < LL; ++l) acc += enc[((size_t)b * LL + l) * ED + tid];
  pooled[tid] = acc * (1.0f / 512.0f);
  __syncthreads();
  float* h0 = (float*)(ws + OFF_H0);
  float* h1 = (float*)(ws + OFF_H1);
  for (int pass = 0; pass < 4; ++pass) {
    const int jj = pass * 256 + tid;
    float a = binit[jj];
    const float* wr = Winit + (size_t)jj * ED;
    for (int e = 0; e < ED; ++e) a += wr[e] * pooled[e];
    const float val = tanh_fast(a);
    const int nl = jj >> 9, h = jj & 511;
    if (nl == 0) h0[(size_t)b * HH + h] = val;
    else h1[(size_t)b * HH + h] = val;
  }
}

// ---------------- main decoder: one block per batch ----------------
__launch_bounds__(NT, 1)
__global__ void k_decode(char* ws, const int* targets, const float* vvec,
                         const float* bhh0, const float* bhh1, const float* bih1,
                         const float* Wout, const float* bout, float* out) {
  extern __shared__ char smem[];
  const int tid = threadIdx.x;
  const int b = blockIdx.x;

  const unsigned short* keysf = (const unsigned short*)(ws + OFF_KEYS) + (size_t)b * LL * HH;
  const unsigned short* enctf = (const unsigned short*)(ws + OFF_ENCT) + (size_t)b * ED * LL;
  const unsigned short* WhF  = (const unsigned short*)(ws + OFF_WH);
  const unsigned short* W0F  = (const unsigned short*)(ws + OFF_WHH0);
  const unsigned short* W1F  = (const unsigned short*)(ws + OFF_WHH1);
  const unsigned short* Wi1F = (const unsigned short*)(ws + OFF_WIH1);
  const unsigned short* WicF = (const unsigned short*)(ws + OFF_WIHC);
  const float* gtok = (const float*)(ws + OFF_GTOK);

  float* h0f  = (float*)(smem + L_H0F);
  float* h1f  = (float*)(smem + L_H1F);
  uint*  h0h  = (uint*)(smem + L_H0H);
  uint*  h1h  = (uint*)(smem + L_H1H);
  float* qb   = (float*)(smem + L_QB);
  float* vvf  = (float*)(smem + L_VV);
  float* scb  = (float*)(smem + L_SCB);
  float* atb  = (float*)(smem + L_ATB);
  float* ctxf = (float*)(smem + L_CTXF);
  uint*  ctxh = (uint*)(smem + L_CTXH);
  float* gh0b = (float*)(smem + L_GH0);
  float* gh1b = (float*)(smem + L_GH1);
  float* gi0b = (float*)(smem + L_GI0);
  float* gi1b = (float*)(smem + L_GI1);
  float* wred = (float*)(smem + L_WRED);

  // ---- preload state ----
  if (tid < 512) {
    h0f[tid] = ((const float*)(ws + OFF_H0))[(size_t)b * HH + tid];
    h1f[tid] = ((const float*)(ws + OFF_H1))[(size_t)b * HH + tid];
    vvf[(tid >> 7) * 132 + (tid & 127)] = vvec[tid];
  }
  __syncthreads();
  if (tid < 256) h0h[tid] = packh(h0f[2 * tid], h0f[2 * tid + 1]);
  else if (tid < 512) { const int i = tid - 256; h1h[i] = packh(h1f[2 * i], h1f[2 * i + 1]); }
  __syncthreads();

  for (int t = 0; t < LL; ++t) {
    // ===== P1: q = Wh@h1, gh0 = Whh0@h0 + bhh0, gh1 = Whh1@h1 + bhh1 =====
    // 3584 rows x 2 k-halves = 7168 slots, 7 per thread.
    for (int p = 0; p < 7; ++p) {
      const int s = p * NT + tid;
      const int row = s >> 1, kh = s & 1;
      const unsigned short* wr;
      const uint* hh;
      if (row < 512)       { wr = WhF + (size_t)row * 512;          hh = h1h; }
      else if (row < 2048) { wr = W0F + (size_t)(row - 512) * 512;  hh = h0h; }
      else                 { wr = W1F + (size_t)(row - 2048) * 512; hh = h1h; }
      wr += kh * 256; hh += kh * 128;
      float acc = 0.f;
      #pragma unroll 8
      for (int c = 0; c < 32; ++c) {
        const uint4 w4 = *(const uint4*)(wr + c * 8);
        const uint4 h4 = *(const uint4*)(hh + c * 4);
        acc = fd2(w4.x, h4.x, acc);
        acc = fd2(w4.y, h4.y, acc);
        acc = fd2(w4.z, h4.z, acc);
        acc = fd2(w4.w, h4.w, acc);
      }
      acc += __shfl_xor(acc, 1);
      if (kh == 0) {
        if (row < 512) qb[(row >> 7) * 132 + (row & 127)] = acc;
        else if (row < 2048) { const int r2 = row - 512; gh0b[r2] = acc + bhh0[r2]; }
        else { const int r2 = row - 2048; gh1b[r2] = acc + bhh1[r2]; }
      }
    }
    __syncthreads();

    // ===== P2: scores[l] = sum_h v[h]*tanh(q[h]+keys[l][h]) =====
    // 512 l x 4 h-quarters = 2048 slots, 2 per thread.
    for (int p = 0; p < 2; ++p) {
      const int s = p * NT + tid;
      const int l = s >> 2, hq = s & 3;
      const unsigned short* kr = keysf + (size_t)l * HH + hq * 128;
      const float* qh = qb + hq * 132;
      const float* vh = vvf + hq * 132;
      float sa = 0.f;
      for (int i8 = 0; i8 < 16; ++i8) {
        const ushort8 kk = *(const ushort8*)(kr + i8 * 8);
        #pragma unroll
        for (int u = 0; u < 8; ++u)
          sa += vh[i8 * 8 + u] * tanh_fast(qh[i8 * 8 + u] + h2f(kk[u]));
      }
      sa += __shfl_xor(sa, 1);
      sa += __shfl_xor(sa, 2);
      if (hq == 0) scb[l] = sa;
    }
    __syncthreads();

    // ===== P3a: exp (|s| <= sum|v| ~ 20, no max pass) + block sum =====
    {
      float e = 0.f;
      if (tid < 512) { e = exp_fast(scb[tid]); atb[(tid >> 7) * 132 + (tid & 127)] = e; }
      float s2 = e;
      #pragma unroll
      for (int off = 32; off >= 1; off >>= 1) s2 += __shfl_xor(s2, off);
      if (tid < 512 && (tid & 63) == 0) wred[tid >> 6] = s2;
    }
    __syncthreads();

    // ===== P3b: ctx[e] = (1/S) * sum_l attn[l]*encT[e][l] =====
    {
      const float S = ((wred[0] + wred[1]) + (wred[2] + wred[3]))
                    + ((wred[4] + wred[5]) + (wred[6] + wred[7]));
      const float rS = __builtin_amdgcn_rcpf(S);
      const int e2 = tid >> 2, lq = tid & 3;
      const unsigned short* er = enctf + (size_t)e2 * LL + lq * 128;
      const float* ap = atb + lq * 132;
      float acc = 0.f;
      for (int i8 = 0; i8 < 16; ++i8) {
        const ushort8 ee = *(const ushort8*)(er + i8 * 8);
        #pragma unroll
        for (int u = 0; u < 8; ++u)
          acc += ap[i8 * 8 + u] * h2f(ee[u]);
      }
      acc += __shfl_xor(acc, 1);
      acc += __shfl_xor(acc, 2);
      if (lq == 0) ctxf[e2] = acc * rS;
    }
    __syncthreads();
    if (tid < 128) ctxh[tid] = packh(ctxf[2 * tid], ctxf[2 * tid + 1]);
    __syncthreads();

    // ===== P4a: gi0 = WihC @ ctx  (1536 rows x 2 kh of 128) =====
    for (int p = 0; p < 3; ++p) {
      const int s = p * NT + tid;
      const int row = s >> 1, kh = s & 1;
      const unsigned short* wr = WicF + (size_t)row * 256 + kh * 128;
      const uint* hh = ctxh + kh * 64;
      float acc = 0.f;
      #pragma unroll 4
      for (int c = 0; c < 16; ++c) {
        const uint4 w4 = *(const uint4*)(wr + c * 8);
        const uint4 h4 = *(const uint4*)(hh + c * 4);
        acc = fd2(w4.x, h4.x, acc);
        acc = fd2(w4.y, h4.y, acc);
        acc = fd2(w4.z, h4.z, acc);
        acc = fd2(w4.w, h4.w, acc);
      }
      acc += __shfl_xor(acc, 1);
      if (kh == 0) gi0b[row] = acc;
    }
    __syncthreads();

    // ===== P4b: layer-0 gates -> h0(t) =====
    if (tid < 512) {
      const int h = tid;
      const int tok = (t == 0) ? SOS : targets[(size_t)b * LL + t - 1];
      const float* gt = gtok + (size_t)tok * 1536;
      const float rg = sigmoid_fast(gi0b[h] + gt[h] + gh0b[h]);
      const float zg = sigmoid_fast(gi0b[512 + h] + gt[512 + h] + gh0b[512 + h]);
      const float ng = tanh_fast(gi0b[1024 + h] + gt[1024 + h] + rg * gh0b[1024 + h]);
      h0f[h] = (1.f - zg) * ng + zg * h0f[h];
    }
    __syncthreads();
    if (tid < 256) h0h[tid] = packh(h0f[2 * tid], h0f[2 * tid + 1]);
    __syncthreads();

    // ===== P5a: gi1 = Wih1 @ h0(t)  (1536 rows x 2 kh of 256) =====
    for (int p = 0; p < 3; ++p) {
      const int s = p * NT + tid;
      const int row = s >> 1, kh = s & 1;
      const unsigned short* wr = Wi1F + (size_t)row * 512 + kh * 256;
      const uint* hh = h0h + kh * 128;
      float acc = 0.f;
      #pragma unroll 8
      for (int c = 0; c < 32; ++c) {
        const uint4 w4 = *(const uint4*)(wr + c * 8);
        const uint4 h4 = *(const uint4*)(hh + c * 4);
        acc = fd2(w4.x, h4.x, acc);
        acc = fd2(w4.y, h4.y, acc);
        acc = fd2(w4.z, h4.z, acc);
        acc = fd2(w4.w, h4.w, acc);
      }
      acc += __shfl_xor(acc, 1);
      if (kh == 0) gi1b[row] = acc;
    }
    __syncthreads();

    // ===== P5b: layer-1 gates -> h1(t) =====
    if (tid < 512) {
      const int h = tid;
      const float rg = sigmoid_fast(gi1b[h] + bih1[h] + gh1b[h]);
      const float zg = sigmoid_fast(gi1b[512 + h] + bih1[512 + h] + gh1b[512 + h]);
      const float ng = tanh_fast(gi1b[1024 + h] + bih1[1024 + h] + rg * gh1b[1024 + h]);
      h1f[h] = (1.f - zg) * ng + zg * h1f[h];
    }
    __syncthreads();

    // ===== P6: repack h1 + logits =====
    if (tid < 256) {
      h1h[tid] = packh(h1f[2 * tid], h1f[2 * tid + 1]);
    } else if (tid < 512) {
      const int lane = tid - 256;
      const int v = lane >> 6, i = lane & 63;
      float a = 0.f;
      #pragma unroll
      for (int k = 0; k < 8; ++k)
        a += Wout[(size_t)v * HH + i * 8 + k] * h1f[i * 8 + k];
      a += __shfl_xor(a, 32); a += __shfl_xor(a, 16); a += __shfl_xor(a, 8);
      a += __shfl_xor(a, 4);  a += __shfl_xor(a, 2);  a += __shfl_xor(a, 1);
      if (i == 0) out[((size_t)b * LL + t) * VV + v] = a + bout[v];
    }
    __syncthreads();
  }
}

// ---------------- launch ----------------
extern "C" void kernel_launch(void* const* d_in, const int* in_sizes, int n_in,
                              void* d_out, int out_size, void* d_ws, size_t ws_size,
                              hipStream_t stream) {
  char* ws = (char*)d_ws;
  const float* enc     = (const float*)d_in[0];
  const int*   targets = (const int*)d_in[1];
  const float* emb   = (const float*)d_in[4];
  const float* Wh    = (const float*)d_in[5];
  const float* Ws    = (const float*)d_in[6];
  const float* vvec  = (const float*)d_in[7];
  const float* Wih0  = (const float*)d_in[8];
  const float* Whh0  = (const float*)d_in[9];
  const float* bih0  = (const float*)d_in[10];
  const float* bhh0  = (const float*)d_in[11];
  const float* Wih1  = (const float*)d_in[12];
  const float* Whh1  = (const float*)d_in[13];
  const float* bih1  = (const float*)d_in[14];
  const float* bhh1  = (const float*)d_in[15];
  const float* Wout  = (const float*)d_in[16];
  const float* bout  = (const float*)d_in[17];
  const float* Winit = (const float*)d_in[18];
  const float* binit = (const float*)d_in[19];

  k_prep <<<1024, 256, 0, stream>>>(Wh, Whh0, Whh1, Wih1, Wih0, ws);
  k_keys <<<1024, 256, 0, stream>>>(enc, Ws, ws);
  k_encT <<<2048, 256, 0, stream>>>(enc, ws);
  k_gitok<<<6,    256, 0, stream>>>(emb, Wih0, bih0, ws);
  k_init <<<64,   256, 0, stream>>>(enc, Winit, binit, ws);

  k_decode<<<dim3(BB), dim3(NT), L_TOT, stream>>>(
      ws, targets, vvec, bhh0, bhh1, bih1, Wout, bout, (float*)d_out);
}

// Round 12
// 53333.990 us; speedup vs baseline: 1.9604x; 1.9604x over previous
//
#include <hip/hip_runtime.h>
#include <cstdint>
#include <cstddef>

// GRU decoder w/ Bahdanau attention, B=64 L=512 E=128 H=512 ENC=256 V=4 NL=2.
// R12 = R11 (octet decomposition + two batches per block, phase-interleaved
// to hide crossing latency) with the LDS overflow FIXED: O_PRED restored to
// 4096 B (ctx-merge uses pRed[0..1023]; R11's 768-float buffer trampled
// gh0own/gh1own). 256 blocks x 256 threads, 1 block/CU, ~158KB LDS.

#define BB   64
#define LL   512
#define EE   128
#define HH   512
#define ED   256
#define VV   4
#define SOS  4

#define NBLK 256
#define NTHR 256

typedef unsigned short ushort8 __attribute__((ext_vector_type(8)));
typedef unsigned int uint;
typedef uint  uint4v  __attribute__((ext_vector_type(4)));
typedef float float4v __attribute__((ext_vector_type(4)));
typedef _Float16 h2v __attribute__((ext_vector_type(2)));

// ---------------- ws layout (bytes) ----------------
static const size_t OFF_KEYS = 0;          // bf16 [64][512][512] 33,554,432
static const size_t OFF_WH   = 33554432;   // bf16 [512][512]        524,288
static const size_t OFF_WHH0 = 34078720;   // f16 [1536][512]      1,572,864
static const size_t OFF_WIH1 = 35651584;   // f16 [1536][512]      1,572,864
static const size_t OFF_WHH1 = 37224448;   // f16 [1536][512]      1,572,864
static const size_t OFF_WIHC = 38797312;   // f16 [1536][256]        786,432
static const size_t OFF_GTOK = 39583744;   // f32 [6][1536]           36,864
static const size_t OFF_H0   = 39620608;   // f32 [64][512]          131,072
static const size_t OFF_H1   = 39751680;   // f32 [64][512]          131,072
static const size_t OFF_QQ   = 39882752;   // uint [64][8][256]      524,288
static const size_t OFF_CTXP = 40407040;   // f32 [64][8][256]       524,288
static const size_t OFF_SS   = 40931328;   // f32 [64][8]              2,048
static const size_t OFF_H0Q  = 40933376;   // uint [64][8][32]        65,536
static const size_t OFF_H1Q  = 40998912;   // uint [64][8][32]        65,536
static const size_t OFF_FLG  = 41064448;   // 64*8 x 64B              32,768
static const size_t OFF_CNT  = 41097216;   // 8 x 64B                    512
static const size_t OFF_LP   = 41097728;   // f32 [512][64][8][4]  4,194,304

// ---------------- dynamic LDS layout ----------------
// keys: 2 x 65536 at 0. per-batch scratch block (12544 B) at 131072+bi*12544.
#define LKEY(bi)  ((bi) * 65536)
#define LB(bi)    (131072 + (bi) * 12544)
#define O_H0U  0      // uint[256] f16-pairs
#define O_H1U  1024   // uint[256]
#define O_QBF  2048   // f32 [4][132]
#define O_CTX  4160   // f32 [256]
#define O_SCB  5184   // f32 [64]
#define O_ATB  5440   // f32 [64]
#define O_WRED 5696   // f32 [16]
#define O_PRED 5760   // f32 [1024]  (ctx merge needs 1024; also qstage)
#define O_GH0  9856   // f32 [192]
#define O_GH1  10624  // f32 [192]
#define O_H0O  11392  // f32 [64]
#define O_H1O  11648  // f32 [64]
#define O_HST  11904  // uint[32]
#define O_CTXH 12032  // uint[128] f16-pairs
// per-batch block ends at 12544
#define L_VV   156160 // f32 [4][132] shared
#define L_TOT  158272

// ---------------- uncached vectorized ops (R9-proven) ----------------
#define UC_LD4(dst, ptr) \
  asm volatile("global_load_dwordx4 %0, %1, off sc0 sc1" : "=v"(dst) : "v"(ptr))
#define UC_ST4(ptr, v4) \
  asm volatile("global_store_dwordx4 %0, %1, off sc0 sc1" :: "v"(ptr), "v"(v4) : "memory")
#define UC_FENCE() \
  do { asm volatile("s_waitcnt vmcnt(0)" ::: "memory"); \
       __builtin_amdgcn_sched_barrier(0); } while (0)

// ---------------- helpers ----------------
__device__ __forceinline__ float bfu(unsigned short u) {
  return __uint_as_float(((unsigned)u) << 16);
}
__device__ __forceinline__ float bflo(uint u) { return __uint_as_float(u << 16); }
__device__ __forceinline__ float bfhi(uint u) { return __uint_as_float(u & 0xffff0000u); }
__device__ __forceinline__ unsigned short f2bf(float f) {
  unsigned u = __float_as_uint(f);
  unsigned r = 0x7FFFu + ((u >> 16) & 1u);
  return (unsigned short)((u + r) >> 16);
}
__device__ __forceinline__ uint packbf(float a, float b) {
  return (uint)f2bf(a) | ((uint)f2bf(b) << 16);
}
__device__ __forceinline__ unsigned short f2h(float f) {
  return __builtin_bit_cast(unsigned short, (_Float16)f);
}
__device__ __forceinline__ uint packh(float a, float b) {
  return (uint)f2h(a) | ((uint)f2h(b) << 16);
}
__device__ __forceinline__ float fd2(uint w, uint h, float acc) {
#if __has_builtin(__builtin_amdgcn_fdot2)
  return __builtin_amdgcn_fdot2(__builtin_bit_cast(h2v, w),
                                __builtin_bit_cast(h2v, h), acc, false);
#else
  acc += (float)__builtin_bit_cast(_Float16, (unsigned short)(w & 0xffffu)) *
         (float)__builtin_bit_cast(_Float16, (unsigned short)(h & 0xffffu));
  acc += (float)__builtin_bit_cast(_Float16, (unsigned short)(w >> 16)) *
         (float)__builtin_bit_cast(_Float16, (unsigned short)(h >> 16));
  return acc;
#endif
}
__device__ __forceinline__ float tanh_fast(float x) {
  x = __builtin_amdgcn_fmed3f(x, -10.f, 10.f);
  float t = __builtin_amdgcn_exp2f(x * 2.8853900817779268f);
  return (t - 1.f) * __builtin_amdgcn_rcpf(t + 1.f);
}
__device__ __forceinline__ float sigmoid_fast(float x) {
  x = __builtin_amdgcn_fmed3f(x, -30.f, 30.f);
  float t = __builtin_amdgcn_exp2f(x * -1.4426950408889634f);
  return __builtin_amdgcn_rcpf(1.f + t);
}
__device__ __forceinline__ float exp_fast(float x) {
  return __builtin_amdgcn_exp2f(x * 1.4426950408889634f);
}
__device__ __forceinline__ float gloadf(const float* p) {
  return __hip_atomic_load(p, __ATOMIC_RELAXED, __HIP_MEMORY_SCOPE_AGENT);
}
__device__ __forceinline__ void gstoref(float* p, float v) {
  __hip_atomic_store(p, v, __ATOMIC_RELAXED, __HIP_MEMORY_SCOPE_AGENT);
}
__device__ __forceinline__ uint gloadu(const uint* p) {
  return __hip_atomic_load(p, __ATOMIC_RELAXED, __HIP_MEMORY_SCOPE_AGENT);
}
__device__ __forceinline__ void gstoreu(uint* p, uint v) {
  __hip_atomic_store(p, v, __ATOMIC_RELAXED, __HIP_MEMORY_SCOPE_AGENT);
}

// publish: drain data stores, block-sync, tid0 raises this member's flag.
__device__ __forceinline__ void oct_publish(char* ws, int b, int j, uint gen) {
  asm volatile("s_waitcnt vmcnt(0)" ::: "memory");
  __syncthreads();
  if (threadIdx.x == 0)
    gstoreu((uint*)(ws + OFF_FLG) + (size_t)(b * 8 + j) * 16, gen);
}
// wait: 8 lanes poll the octet's flags in parallel.
__device__ __forceinline__ void oct_wait(char* ws, int b, uint gen) {
  if (threadIdx.x < 8) {
    const uint* fp = (const uint*)(ws + OFF_FLG) + (size_t)(b * 8 + threadIdx.x) * 16;
    while (gloadu(fp) < gen) __builtin_amdgcn_s_sleep(1);
  }
  __syncthreads();
}

// ---------------- precompute kernels ----------------

__global__ void k_prep(const float* Wh, const float* Whh0, const float* Wih0,
                       const float* Wih1, const float* Whh1, char* ws) {
  unsigned short* Whbf  = (unsigned short*)(ws + OFF_WH);
  unsigned short* W0F   = (unsigned short*)(ws + OFF_WHH0);
  unsigned short* Wi1F  = (unsigned short*)(ws + OFF_WIH1);
  unsigned short* W1F   = (unsigned short*)(ws + OFF_WHH1);
  unsigned short* WicF  = (unsigned short*)(ws + OFF_WIHC);
  const int tot = 262144 + 786432 * 3 + 393216;
  for (int i = blockIdx.x * blockDim.x + threadIdx.x; i < tot; i += gridDim.x * blockDim.x) {
    if (i < 262144) { Whbf[i] = f2bf(Wh[i]); }
    else if (i < 262144 + 786432) { int jj = i - 262144; W0F[jj] = f2h(Whh0[jj]); }
    else if (i < 262144 + 2 * 786432) { int jj = i - 262144 - 786432; Wi1F[jj] = f2h(Wih1[jj]); }
    else if (i < 262144 + 3 * 786432) { int jj = i - 262144 - 2 * 786432; W1F[jj] = f2h(Whh1[jj]); }
    else {
      int jj = i - 262144 - 3 * 786432;
      int r = jj >> 8, e = jj & 255;
      WicF[jj] = f2h(Wih0[(size_t)r * 384 + 128 + e]);
    }
  }
}

__global__ void k_gitok(const float* emb, const float* Wih0, const float* bih0, char* ws) {
  float* gt = (float*)(ws + OFF_GTOK);
  const int vt = blockIdx.x;
  const int tid = threadIdx.x;
  __shared__ float ev[EE];
  if (tid < EE) ev[tid] = emb[(size_t)vt * EE + tid];
  __syncthreads();
  for (int r = tid; r < 1536; r += 256) {
    float a = bih0[r];
    const float* wr = Wih0 + (size_t)r * 384;
    for (int e = 0; e < EE; ++e) a += wr[e] * ev[e];
    gt[(size_t)vt * 1536 + r] = a;
  }
}

__global__ void k_keys(const float* enc, const float* Ws, char* ws) {
  unsigned short* keys = (unsigned short*)(ws + OFF_KEYS);
  __shared__ float et[32][ED];
  const int tid = threadIdx.x;
  const int row0 = blockIdx.x * 32;
  for (int r = 0; r < 32; ++r) et[r][tid] = enc[(size_t)(row0 + r) * ED + tid];
  __syncthreads();
  for (int hhh = 0; hhh < 2; ++hhh) {
    const int h = hhh * 256 + tid;
    float acc[32];
    #pragma unroll
    for (int ll = 0; ll < 32; ++ll) acc[ll] = 0.f;
    const float4* wrow = (const float4*)(Ws + (size_t)h * ED);
    for (int e4 = 0; e4 < 64; ++e4) {
      float4 w = wrow[e4];
      #pragma unroll
      for (int ll = 0; ll < 32; ++ll) {
        acc[ll] += w.x * et[ll][e4 * 4] + w.y * et[ll][e4 * 4 + 1]
                 + w.z * et[ll][e4 * 4 + 2] + w.w * et[ll][e4 * 4 + 3];
      }
    }
    for (int ll = 0; ll < 32; ++ll)
      keys[(size_t)(row0 + ll) * HH + h] = f2bf(acc[ll]);
  }
}

__global__ void k_init(const float* enc, const float* Winit, const float* binit, char* ws) {
  const int b = blockIdx.x;
  const int tid = threadIdx.x; // 256
  __shared__ float pooled[ED];
  float acc = 0.f;
  for (int l = 0; l < LL; ++l) acc += enc[((size_t)b * LL + l) * ED + tid];
  pooled[tid] = acc * (1.0f / 512.0f);
  __syncthreads();
  float* h0 = (float*)(ws + OFF_H0);
  float* h1 = (float*)(ws + OFF_H1);
  for (int pass = 0; pass < 4; ++pass) {
    const int jj = pass * 256 + tid;
    float a = binit[jj];
    const float* wr = Winit + (size_t)jj * ED;
    for (int e = 0; e < ED; ++e) a += wr[e] * pooled[e];
    const float val = tanh_fast(a);
    const int nl = jj >> 9, h = jj & 511;
    if (nl == 0) h0[(size_t)b * HH + h] = val;
    else h1[(size_t)b * HH + h] = val;
  }
  if (b == 0) {
    uint* fl = (uint*)(ws + OFF_FLG);
    for (int i = tid; i < 8192; i += 256) fl[i] = 0u;
    uint* cnt = (uint*)(ws + OFF_CNT);
    if (tid < 128) cnt[tid] = 0u;
  }
}

// ---------------- main persistent decoder ----------------
__launch_bounds__(NTHR, 1)
__global__ void k_decode(char* ws, const float* enc, const int* targets,
                         const float* vvec, const float* bhh0, const float* bhh1,
                         const float* bih1, const float* Wout) {
  extern __shared__ char smem[];
  const int tid = threadIdx.x;

  // roles: j = XCC_ID; pair = per-XCD rank (0..31); batches 2*pair, 2*pair+1.
  __shared__ int roleSh[2];
  if (tid == 0) {
    uint xcd;
    asm volatile("s_getreg_b32 %0, hwreg(HW_REG_XCC_ID)" : "=s"(xcd));
    xcd &= 7u;
    uint* cnt = (uint*)(ws + OFF_CNT);
    uint rank = __hip_atomic_fetch_add(cnt + (size_t)xcd * 16, 1u,
                                       __ATOMIC_RELAXED, __HIP_MEMORY_SCOPE_AGENT);
    roleSh[0] = (int)(rank & 31);
    roleSh[1] = (int)xcd;
  }
  __syncthreads();
  const int pair = roleSh[0], j = roleSh[1];
  const int bat[2] = { pair * 2, pair * 2 + 1 };

  const unsigned short* keysg = (const unsigned short*)(ws + OFF_KEYS);
  const unsigned short* Whbf  = (const unsigned short*)(ws + OFF_WH);
  const unsigned short* W0F   = (const unsigned short*)(ws + OFF_WHH0);
  const unsigned short* Wi1F  = (const unsigned short*)(ws + OFF_WIH1);
  const unsigned short* W1F   = (const unsigned short*)(ws + OFF_WHH1);
  const unsigned short* WicF  = (const unsigned short*)(ws + OFF_WIHC);
  const float* gi_tok = (const float*)(ws + OFF_GTOK);
  float* lp = (float*)(ws + OFF_LP);
  float* vvf = (float*)(smem + L_VV);

  // Wh slice regs (batch-independent): rows 2tid,2tid+1, cols [j*64,+64) bf16
  uint whq[64];
  #pragma unroll
  for (int i = 0; i < 32; ++i) {
    whq[i]      = *(const uint*)(Whbf + (size_t)(2 * tid) * HH + j * 64 + 2 * i);
    whq[32 + i] = *(const uint*)(Whbf + (size_t)(2 * tid + 1) * HH + j * 64 + 2 * i);
  }
  for (int h = tid; h < 512; h += NTHR)
    vvf[(h >> 7) * 132 + (h & 127)] = vvec[h];

  // enc slices -> regs (both batches)
  uint encp[2][32];
  #pragma unroll
  for (int bi = 0; bi < 2; ++bi) {
    const float* ebase = enc + ((size_t)(bat[bi] * LL + j * 64)) * ED + tid;
    #pragma unroll
    for (int k = 0; k < 32; ++k)
      encp[bi][k] = packbf(ebase[(size_t)(2 * k) * ED], ebase[(size_t)(2 * k + 1) * ED]);
  }

  // preloads + pre-loop publish per batch
  #pragma unroll
  for (int bi = 0; bi < 2; ++bi) {
    const int b = bat[bi];
    char* bb = smem + LB(bi);
    uint*  h0u = (uint*)(bb + O_H0U);
    uint*  h1u = (uint*)(bb + O_H1U);
    float* h0own = (float*)(bb + O_H0O);
    float* h1own = (float*)(bb + O_H1O);
    uint*  qstage = (uint*)(bb + O_PRED);
    uint*  hstage = (uint*)(bb + O_HST);
    // keys eighth -> LDS swizzled
    for (int c = tid; c < 4096; c += NTHR) {
      const int l = c >> 6, hs = c & 63;
      ushort8 kv = *(const ushort8*)(keysg + ((size_t)(b * LL + j * 64 + l) * HH + hs * 8));
      *(ushort8*)(smem + LKEY(bi) + l * 1024 + ((hs * 16) ^ ((l & 7) << 4))) = kv;
    }
    const float* H0g = (const float*)(ws + OFF_H0) + (size_t)b * HH;
    const float* H1g = (const float*)(ws + OFF_H1) + (size_t)b * HH;
    h0u[tid] = packh(H0g[2 * tid], H0g[2 * tid + 1]);
    h1u[tid] = packh(H1g[2 * tid], H1g[2 * tid + 1]);
    if (tid < 64) {
      h0own[tid] = H0g[j * 64 + tid];
      h1own[tid] = H1g[j * 64 + tid];
    }
    __syncthreads();
    // q partials from initial h1own
    {
      float q0 = 0.f, q1 = 0.f;
      #pragma unroll
      for (int i = 0; i < 32; ++i) {
        const float hl = h1own[2 * i], hh = h1own[2 * i + 1];
        q0 += bflo(whq[i]) * hl + bfhi(whq[i]) * hh;
        q1 += bflo(whq[32 + i]) * hl + bfhi(whq[32 + i]) * hh;
      }
      qstage[tid] = packbf(q0, q1);
      if (tid < 32) hstage[tid] = packh(h1own[2 * tid], h1own[2 * tid + 1]);
    }
    __syncthreads();
    uint* QQg  = (uint*)(ws + OFF_QQ)  + (size_t)b * 2048;
    uint* H1Qg = (uint*)(ws + OFF_H1Q) + (size_t)b * 256;
    if (tid < 64) { UC_ST4(QQg + (size_t)j * 256 + 4 * tid, *(uint4v*)(qstage + 4 * tid)); }
    else if (tid < 72) {
      const int c = tid - 64;
      UC_ST4(H1Qg + (size_t)j * 32 + 4 * c, *(uint4v*)(hstage + 4 * c));
    }
    oct_publish(ws, b, j, 2u);
  }

  for (int t = 0; t < LL; ++t) {
    // =================== PHASE A (both batches) ===================
    #pragma unroll
    for (int bi = 0; bi < 2; ++bi) {
      const int b = bat[bi];
      char* bb = smem + LB(bi);
      uint*  h0u = (uint*)(bb + O_H0U);
      uint*  h1u = (uint*)(bb + O_H1U);
      float* qbf = (float*)(bb + O_QBF);
      float* ctx = (float*)(bb + O_CTX);
      float* scb = (float*)(bb + O_SCB);
      float* atb = (float*)(bb + O_ATB);
      float* pRed = (float*)(bb + O_PRED);
      float* gh0own = (float*)(bb + O_GH0);
      float* gh1own = (float*)(bb + O_GH1);
      uint* QQg  = (uint*)(ws + OFF_QQ)  + (size_t)b * 2048;
      uint* H1Qg = (uint*)(ws + OFF_H1Q) + (size_t)b * 256;
      float* CTXPg = (float*)(ws + OFF_CTXP) + (size_t)b * 2048;
      float* SSg = (float*)(ws + OFF_SS) + (size_t)b * 8;

      oct_wait(ws, b, 2u + 3u * (uint)t);

      // A1: q assembly (x4) + sibling h1
      if (tid < 64) {
        uint4v u0, u1, u2, u3, u4, u5, u6, u7;
        UC_LD4(u0, QQg + 0 * 256 + 4 * tid);
        UC_LD4(u1, QQg + 1 * 256 + 4 * tid);
        UC_LD4(u2, QQg + 2 * 256 + 4 * tid);
        UC_LD4(u3, QQg + 3 * 256 + 4 * tid);
        UC_LD4(u4, QQg + 4 * 256 + 4 * tid);
        UC_LD4(u5, QQg + 5 * 256 + 4 * tid);
        UC_LD4(u6, QQg + 6 * 256 + 4 * tid);
        UC_LD4(u7, QQg + 7 * 256 + 4 * tid);
        UC_FENCE();
        const int base = ((8 * tid) >> 7) * 132 + ((8 * tid) & 127);
        #pragma unroll
        for (int k = 0; k < 4; ++k) {
          float lo = bflo(u0[k]) + bflo(u1[k]) + bflo(u2[k]) + bflo(u3[k])
                   + bflo(u4[k]) + bflo(u5[k]) + bflo(u6[k]) + bflo(u7[k]);
          float hi = bfhi(u0[k]) + bfhi(u1[k]) + bfhi(u2[k]) + bfhi(u3[k])
                   + bfhi(u4[k]) + bfhi(u5[k]) + bfhi(u6[k]) + bfhi(u7[k]);
          qbf[base + 2 * k]     = lo;
          qbf[base + 2 * k + 1] = hi;
        }
      } else if (tid < 120) {
        const int p2 = (tid - 64) >> 3, c = (tid - 64) & 7;
        const int p = p2 + (p2 >= j);
        uint4v u;
        UC_LD4(u, H1Qg + (size_t)p * 32 + 4 * c);
        UC_FENCE();
        *(uint4v*)(h1u + p * 32 + 4 * c) = u;
      }
      __syncthreads();

      // A2: gh0/gh1 K-half partials (f16 dot2)
      {
        const int mat = tid >> 7, seg = (tid >> 6) & 1, r = tid & 63;
        const unsigned short* W = mat ? W1F : W0F;
        const uint* hsrc = (mat ? h1u : h0u) + seg * 128;
        const uint* w0 = (const uint*)(W + (size_t)(0 * 512 + j * 64 + r) * 512 + seg * 256);
        const uint* w1 = (const uint*)(W + (size_t)(1 * 512 + j * 64 + r) * 512 + seg * 256);
        const uint* w2 = (const uint*)(W + (size_t)(2 * 512 + j * 64 + r) * 512 + seg * 256);
        float a0 = 0.f, a1 = 0.f, a2 = 0.f;
        for (int k8 = 0; k8 < 32; ++k8) {
          const uint4 h4 = *(const uint4*)(hsrc + k8 * 4);
          const uint4 x0 = *(const uint4*)(w0 + k8 * 4);
          const uint4 x1 = *(const uint4*)(w1 + k8 * 4);
          const uint4 x2 = *(const uint4*)(w2 + k8 * 4);
          a0 = fd2(x0.x, h4.x, a0); a0 = fd2(x0.y, h4.y, a0);
          a0 = fd2(x0.z, h4.z, a0); a0 = fd2(x0.w, h4.w, a0);
          a1 = fd2(x1.x, h4.x, a1); a1 = fd2(x1.y, h4.y, a1);
          a1 = fd2(x1.z, h4.z, a1); a1 = fd2(x1.w, h4.w, a1);
          a2 = fd2(x2.x, h4.x, a2); a2 = fd2(x2.y, h4.y, a2);
          a2 = fd2(x2.z, h4.z, a2); a2 = fd2(x2.w, h4.w, a2);
        }
        pRed[((mat * 2 + seg) * 3 + 0) * 64 + r] = a0;
        pRed[((mat * 2 + seg) * 3 + 1) * 64 + r] = a1;
        pRed[((mat * 2 + seg) * 3 + 2) * 64 + r] = a2;
      }

      // A3: scores for own l-eighth
      {
        const int lloc = tid >> 2, hq = tid & 3;
        const char* kbase = smem + LKEY(bi) + lloc * 1024;
        const int xo = (lloc & 7) << 4;
        const float* qh = qbf + hq * 132;
        const float* vh = vvf + hq * 132;
        float s = 0.f;
        for (int i8 = 0; i8 < 16; ++i8) {
          ushort8 kk = *(const ushort8*)(kbase + ((hq * 256 + i8 * 16) ^ xo));
          const float* q8 = qh + i8 * 8;
          const float* v8 = vh + i8 * 8;
          #pragma unroll
          for (int u = 0; u < 8; ++u)
            s += v8[u] * tanh_fast(q8[u] + bfu(kk[u]));
        }
        s += __shfl_xor(s, 1);
        s += __shfl_xor(s, 2);
        if (hq == 0) scb[lloc] = s;
      }
      __syncthreads();

      // A4: exp + sum -> SS
      if (tid < 64) {
        float e = exp_fast(scb[tid]);
        atb[tid] = e;
        float s2 = e;
        #pragma unroll
        for (int off = 32; off >= 1; off >>= 1) s2 += __shfl_xor(s2, off);
        if (tid == 0) gstoref(SSg + j, s2);
      }
      __syncthreads();

      // A5: ctx partial -> stage; gh reduce
      {
        float a = 0.f;
        #pragma unroll
        for (int k = 0; k < 32; ++k) {
          uint u = encp[bi][k];
          a += atb[2 * k] * bflo(u) + atb[2 * k + 1] * bfhi(u);
        }
        ctx[tid] = a;
      }
      for (int o = tid; o < 384; o += NTHR) {
        const int m = (o >= 192) ? 1 : 0, oo = o - m * 192, g = oo >> 6, r = oo & 63;
        const float v = pRed[((m * 2 + 0) * 3 + g) * 64 + r]
                      + pRed[((m * 2 + 1) * 3 + g) * 64 + r]
                      + (m ? bhh1 : bhh0)[g * 512 + j * 64 + r];
        (m ? gh1own : gh0own)[g * 64 + r] = v;
      }
      __syncthreads();
      if (tid < 64) { UC_ST4((uint*)(CTXPg + (size_t)j * 256) + 4 * tid, *(uint4v*)((uint*)ctx + 4 * tid)); }
      oct_publish(ws, b, j, 3u + 3u * (uint)t);
    }

    // =================== PHASE B (both batches) ===================
    #pragma unroll
    for (int bi = 0; bi < 2; ++bi) {
      const int b = bat[bi];
      char* bb = smem + LB(bi);
      uint*  h0u = (uint*)(bb + O_H0U);
      float* ctx = (float*)(bb + O_CTX);
      uint*  ctxh = (uint*)(bb + O_CTXH);
      float* wred = (float*)(bb + O_WRED);
      float* pRed = (float*)(bb + O_PRED);
      float* gh0own = (float*)(bb + O_GH0);
      float* h0own = (float*)(bb + O_H0O);
      uint*  hstage = (uint*)(bb + O_HST);
      float* CTXPg = (float*)(ws + OFF_CTXP) + (size_t)b * 2048;
      float* SSg = (float*)(ws + OFF_SS) + (size_t)b * 8;
      uint* H0Qg = (uint*)(ws + OFF_H0Q) + (size_t)b * 256;

      oct_wait(ws, b, 3u + 3u * (uint)t);

      // ctx merge (x4) — pRed[0..1023]
      {
        const int c = tid & 63, p0 = tid >> 6;
        float4v f0, f1;
        UC_LD4(f0, (const uint*)(CTXPg + (size_t)p0 * 256) + 4 * c);
        UC_LD4(f1, (const uint*)(CTXPg + (size_t)(p0 + 4) * 256) + 4 * c);
        float ssv = 0.f;
        if (tid < 8) ssv = gloadf(SSg + tid);
        UC_FENCE();
        if (tid < 8) wred[tid] = ssv;
        *(float4v*)(pRed + (size_t)p0 * 256 + 4 * c) = f0 + f1;
        __syncthreads();
        const float S8 = ((wred[0] + wred[1]) + (wred[2] + wred[3]))
                       + ((wred[4] + wred[5]) + (wred[6] + wred[7]));
        const float rS = __builtin_amdgcn_rcpf(S8);
        ctx[tid] = (pRed[0 * 256 + tid] + pRed[1 * 256 + tid]
                  + pRed[2 * 256 + tid] + pRed[3 * 256 + tid]) * rS;
      }
      __syncthreads();
      if (tid < 128) ctxh[tid] = packh(ctx[2 * tid], ctx[2 * tid + 1]);
      __syncthreads();
      // gi0 partials (f16 dot2)
      {
        const int r = tid & 63, q4 = tid >> 6;
        const uint* w0 = (const uint*)(WicF + (size_t)(0 * 512 + j * 64 + r) * 256 + q4 * 64);
        const uint* w1 = (const uint*)(WicF + (size_t)(1 * 512 + j * 64 + r) * 256 + q4 * 64);
        const uint* w2 = (const uint*)(WicF + (size_t)(2 * 512 + j * 64 + r) * 256 + q4 * 64);
        const uint* hh = ctxh + q4 * 32;
        float a0 = 0.f, a1 = 0.f, a2 = 0.f;
        for (int c8 = 0; c8 < 8; ++c8) {
          const uint4 h4 = *(const uint4*)(hh + c8 * 4);
          const uint4 x0 = *(const uint4*)(w0 + c8 * 4);
          const uint4 x1 = *(const uint4*)(w1 + c8 * 4);
          const uint4 x2 = *(const uint4*)(w2 + c8 * 4);
          a0 = fd2(x0.x, h4.x, a0); a0 = fd2(x0.y, h4.y, a0);
          a0 = fd2(x0.z, h4.z, a0); a0 = fd2(x0.w, h4.w, a0);
          a1 = fd2(x1.x, h4.x, a1); a1 = fd2(x1.y, h4.y, a1);
          a1 = fd2(x1.z, h4.z, a1); a1 = fd2(x1.w, h4.w, a1);
          a2 = fd2(x2.x, h4.x, a2); a2 = fd2(x2.y, h4.y, a2);
          a2 = fd2(x2.z, h4.z, a2); a2 = fd2(x2.w, h4.w, a2);
        }
        pRed[(q4 * 3 + 0) * 64 + r] = a0;
        pRed[(q4 * 3 + 1) * 64 + r] = a1;
        pRed[(q4 * 3 + 2) * 64 + r] = a2;
      }
      __syncthreads();
      if (tid < 64) {
        const int r = tid;
        const int tok = (t == 0) ? SOS : targets[(size_t)b * LL + t - 1];
        const float* gt = gi_tok + (size_t)tok * 1536 + j * 64 + r;
        const float g0 = pRed[(0 * 3 + 0) * 64 + r] + pRed[(1 * 3 + 0) * 64 + r]
                       + pRed[(2 * 3 + 0) * 64 + r] + pRed[(3 * 3 + 0) * 64 + r] + gt[0];
        const float g1 = pRed[(0 * 3 + 1) * 64 + r] + pRed[(1 * 3 + 1) * 64 + r]
                       + pRed[(2 * 3 + 1) * 64 + r] + pRed[(3 * 3 + 1) * 64 + r] + gt[512];
        const float g2 = pRed[(0 * 3 + 2) * 64 + r] + pRed[(1 * 3 + 2) * 64 + r]
                       + pRed[(2 * 3 + 2) * 64 + r] + pRed[(3 * 3 + 2) * 64 + r] + gt[1024];
        const float rg = sigmoid_fast(g0 + gh0own[r]);
        const float zg = sigmoid_fast(g1 + gh0own[64 + r]);
        const float ng = tanh_fast(g2 + rg * gh0own[128 + r]);
        h0own[r] = (1.f - zg) * ng + zg * h0own[r];
      }
      __syncthreads();
      if (tid < 32) {
        const uint pk = packh(h0own[2 * tid], h0own[2 * tid + 1]);
        h0u[j * 32 + tid] = pk;
        hstage[tid] = pk;
      }
      __syncthreads();
      if (tid < 8) { UC_ST4(H0Qg + (size_t)j * 32 + 4 * tid, *(uint4v*)(hstage + 4 * tid)); }
      oct_publish(ws, b, j, 4u + 3u * (uint)t);
    }

    // =================== PHASE C (both batches) ===================
    #pragma unroll
    for (int bi = 0; bi < 2; ++bi) {
      const int b = bat[bi];
      char* bb = smem + LB(bi);
      uint*  h0u = (uint*)(bb + O_H0U);
      uint*  h1u = (uint*)(bb + O_H1U);
      float* pRed = (float*)(bb + O_PRED);
      float* gh1own = (float*)(bb + O_GH1);
      float* h1own = (float*)(bb + O_H1O);
      uint*  qstage = (uint*)(bb + O_PRED);
      uint*  hstage = (uint*)(bb + O_HST);
      uint* QQg  = (uint*)(ws + OFF_QQ)  + (size_t)b * 2048;
      uint* H0Qg = (uint*)(ws + OFF_H0Q) + (size_t)b * 256;
      uint* H1Qg = (uint*)(ws + OFF_H1Q) + (size_t)b * 256;

      oct_wait(ws, b, 4u + 3u * (uint)t);

      if (tid < 56) {
        const int p2 = tid >> 3, c = tid & 7;
        const int p = p2 + (p2 >= j);
        uint4v u;
        UC_LD4(u, H0Qg + (size_t)p * 32 + 4 * c);
        UC_FENCE();
        *(uint4v*)(h0u + p * 32 + 4 * c) = u;
      }
      __syncthreads();
      // gi1 partials (f16 dot2)
      {
        const int r = tid & 63, s4 = tid >> 6;
        const uint* w0 = (const uint*)(Wi1F + (size_t)(0 * 512 + j * 64 + r) * 512 + s4 * 128);
        const uint* w1 = (const uint*)(Wi1F + (size_t)(1 * 512 + j * 64 + r) * 512 + s4 * 128);
        const uint* w2 = (const uint*)(Wi1F + (size_t)(2 * 512 + j * 64 + r) * 512 + s4 * 128);
        const uint* hh = h0u + s4 * 64;
        float a0 = 0.f, a1 = 0.f, a2 = 0.f;
        for (int c8 = 0; c8 < 16; ++c8) {
          const uint4 h4 = *(const uint4*)(hh + c8 * 4);
          const uint4 x0 = *(const uint4*)(w0 + c8 * 4);
          const uint4 x1 = *(const uint4*)(w1 + c8 * 4);
          const uint4 x2 = *(const uint4*)(w2 + c8 * 4);
          a0 = fd2(x0.x, h4.x, a0); a0 = fd2(x0.y, h4.y, a0);
          a0 = fd2(x0.z, h4.z, a0); a0 = fd2(x0.w, h4.w, a0);
          a1 = fd2(x1.x, h4.x, a1); a1 = fd2(x1.y, h4.y, a1);
          a1 = fd2(x1.z, h4.z, a1); a1 = fd2(x1.w, h4.w, a1);
          a2 = fd2(x2.x, h4.x, a2); a2 = fd2(x2.y, h4.y, a2);
          a2 = fd2(x2.z, h4.z, a2); a2 = fd2(x2.w, h4.w, a2);
        }
        pRed[(s4 * 3 + 0) * 64 + r] = a0;
        pRed[(s4 * 3 + 1) * 64 + r] = a1;
        pRed[(s4 * 3 + 2) * 64 + r] = a2;
      }
      __syncthreads();
      if (tid < 64) {
        const int r = tid;
        const float g0 = pRed[(0 * 3 + 0) * 64 + r] + pRed[(1 * 3 + 0) * 64 + r]
                       + pRed[(2 * 3 + 0) * 64 + r] + pRed[(3 * 3 + 0) * 64 + r]
                       + bih1[0 * 512 + j * 64 + r];
        const float g1 = pRed[(0 * 3 + 1) * 64 + r] + pRed[(1 * 3 + 1) * 64 + r]
                       + pRed[(2 * 3 + 1) * 64 + r] + pRed[(3 * 3 + 1) * 64 + r]
                       + bih1[1 * 512 + j * 64 + r];
        const float g2 = pRed[(0 * 3 + 2) * 64 + r] + pRed[(1 * 3 + 2) * 64 + r]
                       + pRed[(2 * 3 + 2) * 64 + r] + pRed[(3 * 3 + 2) * 64 + r]
                       + bih1[2 * 512 + j * 64 + r];
        const float rg = sigmoid_fast(g0 + gh1own[r]);
        const float zg = sigmoid_fast(g1 + gh1own[64 + r]);
        const float ng = tanh_fast(g2 + rg * gh1own[128 + r]);
        h1own[r] = (1.f - zg) * ng + zg * h1own[r];
      }
      __syncthreads();
      // q partials (bf16 Wh regs) + stages + logits
      {
        float q0 = 0.f, q1 = 0.f;
        #pragma unroll
        for (int i = 0; i < 32; ++i) {
          const float hl = h1own[2 * i], hh = h1own[2 * i + 1];
          q0 += bflo(whq[i]) * hl + bfhi(whq[i]) * hh;
          q1 += bflo(whq[32 + i]) * hl + bfhi(whq[32 + i]) * hh;
        }
        qstage[tid] = packbf(q0, q1);
      }
      if (tid < 32) {
        const uint pk = packh(h1own[2 * tid], h1own[2 * tid + 1]);
        h1u[j * 32 + tid] = pk;
        hstage[tid] = pk;
      }
      if (tid >= 64 && tid < 128) {
        const int lane = tid - 64, v = lane >> 4, i = lane & 15;
        float a = 0.f;
        #pragma unroll
        for (int k = 0; k < 4; ++k)
          a += Wout[(size_t)v * HH + j * 64 + i * 4 + k] * h1own[i * 4 + k];
        a += __shfl_xor(a, 8); a += __shfl_xor(a, 4);
        a += __shfl_xor(a, 2); a += __shfl_xor(a, 1);
        if (i == 0) lp[(((size_t)t * BB + b) * 8 + j) * 4 + v] = a;
      }
      __syncthreads();
      if (tid < 64) { UC_ST4(QQg + (size_t)j * 256 + 4 * tid, *(uint4v*)(qstage + 4 * tid)); }
      else if (tid < 72) {
        const int c = tid - 64;
        UC_ST4(H1Qg + (size_t)j * 32 + 4 * c, *(uint4v*)(hstage + 4 * c));
      }
      oct_publish(ws, b, j, 5u + 3u * (uint)t);
    }
  }
}

// sum logit partials -> out
__global__ void k_lsum(const char* ws, const float* bout, float* out) {
  const float* lp = (const float*)(ws + OFF_LP);
  const int i = blockIdx.x * 256 + threadIdx.x;
  if (i >= BB * LL * VV) return;
  const int v = i & 3, t = (i >> 2) & 511, b = i >> 11;
  float a = bout[v];
  #pragma unroll
  for (int jj = 0; jj < 8; ++jj)
    a += lp[(((size_t)t * BB + b) * 8 + jj) * 4 + v];
  out[i] = a;
}

// ---------------- launch ----------------
extern "C" void kernel_launch(void* const* d_in, const int* in_sizes, int n_in,
                              void* d_out, int out_size, void* d_ws, size_t ws_size,
                              hipStream_t stream) {
  char* ws = (char*)d_ws;
  const float* enc     = (const float*)d_in[0];
  const int*   targets = (const int*)d_in[1];
  const float* emb   = (const float*)d_in[4];
  const float* Wh    = (const float*)d_in[5];
  const float* Ws    = (const float*)d_in[6];
  const float* vvec  = (const float*)d_in[7];
  const float* Wih0  = (const float*)d_in[8];
  const float* Whh0  = (const float*)d_in[9];
  const float* bih0  = (const float*)d_in[10];
  const float* bhh0  = (const float*)d_in[11];
  const float* Wih1  = (const float*)d_in[12];
  const float* Whh1  = (const float*)d_in[13];
  const float* bih1  = (const float*)d_in[14];
  const float* bhh1  = (const float*)d_in[15];
  const float* Wout  = (const float*)d_in[16];
  const float* bout  = (const float*)d_in[17];
  const float* Winit = (const float*)d_in[18];
  const float* binit = (const float*)d_in[19];

  k_prep <<<1024, 256, 0, stream>>>(Wh, Whh0, Wih0, Wih1, Whh1, ws);
  k_gitok<<<6,    256, 0, stream>>>(emb, Wih0, bih0, ws);
  k_keys <<<1024, 256, 0, stream>>>(enc, Ws, ws);
  k_init <<<64,   256, 0, stream>>>(enc, Winit, binit, ws);

  (void)hipFuncSetAttribute((const void*)k_decode,
                            hipFuncAttributeMaxDynamicSharedMemorySize, L_TOT);

  {
    void* kws = (void*)ws;
    void* ken = (void*)enc;
    void* ktg = (void*)targets;
    void* kvv = (void*)vvec;
    void* kb0 = (void*)bhh0;
    void* kb1 = (void*)bhh1;
    void* kbi = (void*)bih1;
    void* kwo = (void*)Wout;
    void* args[] = { &kws, &ken, &ktg, &kvv, &kb0, &kb1, &kbi, &kwo };
    hipError_t ce = hipLaunchCooperativeKernel((const void*)k_decode, dim3(NBLK), dim3(NTHR),
                                               args, L_TOT, stream);
    if (ce != hipSuccess) {
      // 256 blocks x (256 thr, 158KB LDS) = 1 block/CU on 256 CUs: co-resident
      k_decode<<<dim3(NBLK), dim3(NTHR), L_TOT, stream>>>(ws, enc, targets, vvec,
                                                          bhh0, bhh1, bih1, Wout);
    }
  }

  k_lsum<<<512, 256, 0, stream>>>(ws, bout, (float*)d_out);
}